// Round 2
// baseline (1361.470 us; speedup 1.0000x reference)
//
#include <hip/hip_runtime.h>

#define TT 8

__device__ __forceinline__ float lrelu(float x){ return fmaxf(x, 0.2f*x); }

// One IVP Euler step for N states (N=4 or 2), K-split across 4 waves,
// weights in registers. 6 barriers per step.
template<int N>
__device__ __forceinline__ void ivp_step(
    int tid, int w, int j, float tk, float adt,
    float (&wA1)[16][2], float (&wA2)[32][2], float (&wA3)[32],
    float c_a1, float c_wt, float c_a2, float c_a3,
    float (*zS)[4], float (*h1S)[4], float (*h2iS)[4],
    float (*P)[128][4], float (*P3)[64][4])
{
  float acc0[N], acc1[N];
  #pragma unroll
  for(int e=0;e<N;++e){ acc0[e]=0.f; acc1[e]=0.f; }

  // ---- L1: z(64) -> h1(128), rows [16w,16w+16) ----
  #pragma unroll
  for(int i=0;i<16;++i){
    float zv[N];
    if constexpr(N==4){ float4 t4=*(const float4*)&zS[16*w+i][0]; zv[0]=t4.x; zv[1]=t4.y; zv[2]=t4.z; zv[3]=t4.w; }
    else              { float2 t2=*(const float2*)&zS[16*w+i][0]; zv[0]=t2.x; zv[1]=t2.y; }
    #pragma unroll
    for(int e=0;e<N;++e){
      acc0[e]=fmaf(zv[e], wA1[i][0], acc0[e]);
      acc1[e]=fmaf(zv[e], wA1[i][1], acc1[e]);
    }
  }
  if constexpr(N==4){
    *(float4*)&P[w][2*j  ][0] = make_float4(acc0[0],acc0[1],acc0[2],acc0[3]);
    *(float4*)&P[w][2*j+1][0] = make_float4(acc1[0],acc1[1],acc1[2],acc1[3]);
  } else {
    *(float2*)&P[w][2*j  ][0] = make_float2(acc0[0],acc0[1]);
    *(float2*)&P[w][2*j+1][0] = make_float2(acc1[0],acc1[1]);
  }
  __syncthreads();
  if(tid<128){
    float s[N];
    #pragma unroll
    for(int e=0;e<N;++e)
      s[e]=P[0][tid][e]+P[1][tid][e]+P[2][tid][e]+P[3][tid][e]+tk*c_wt+c_a1;
    if constexpr(N==4) *(float4*)&h1S[tid][0]=make_float4(tanhf(s[0]),tanhf(s[1]),tanhf(s[2]),tanhf(s[3]));
    else               *(float2*)&h1S[tid][0]=make_float2(tanhf(s[0]),tanhf(s[1]));
  }
  __syncthreads();

  // ---- L2: h1(128) -> h2(128), rows [32w,32w+32) ----
  #pragma unroll
  for(int e=0;e<N;++e){ acc0[e]=0.f; acc1[e]=0.f; }
  #pragma unroll
  for(int i=0;i<32;++i){
    float hv[N];
    if constexpr(N==4){ float4 t4=*(const float4*)&h1S[32*w+i][0]; hv[0]=t4.x; hv[1]=t4.y; hv[2]=t4.z; hv[3]=t4.w; }
    else              { float2 t2=*(const float2*)&h1S[32*w+i][0]; hv[0]=t2.x; hv[1]=t2.y; }
    #pragma unroll
    for(int e=0;e<N;++e){
      acc0[e]=fmaf(hv[e], wA2[i][0], acc0[e]);
      acc1[e]=fmaf(hv[e], wA2[i][1], acc1[e]);
    }
  }
  if constexpr(N==4){
    *(float4*)&P[w][2*j  ][0] = make_float4(acc0[0],acc0[1],acc0[2],acc0[3]);
    *(float4*)&P[w][2*j+1][0] = make_float4(acc1[0],acc1[1],acc1[2],acc1[3]);
  } else {
    *(float2*)&P[w][2*j  ][0] = make_float2(acc0[0],acc0[1]);
    *(float2*)&P[w][2*j+1][0] = make_float2(acc1[0],acc1[1]);
  }
  __syncthreads();
  if(tid<128){
    float s[N];
    #pragma unroll
    for(int e=0;e<N;++e)
      s[e]=P[0][tid][e]+P[1][tid][e]+P[2][tid][e]+P[3][tid][e]+c_a2;
    if constexpr(N==4) *(float4*)&h2iS[tid][0]=make_float4(tanhf(s[0]),tanhf(s[1]),tanhf(s[2]),tanhf(s[3]));
    else               *(float2*)&h2iS[tid][0]=make_float2(tanhf(s[0]),tanhf(s[1]));
  }
  __syncthreads();

  // ---- L3: h2(128) -> dz(64), rows [32w,32w+32) ----
  float a3a[N];
  #pragma unroll
  for(int e=0;e<N;++e) a3a[e]=0.f;
  #pragma unroll
  for(int i=0;i<32;++i){
    float hv[N];
    if constexpr(N==4){ float4 t4=*(const float4*)&h2iS[32*w+i][0]; hv[0]=t4.x; hv[1]=t4.y; hv[2]=t4.z; hv[3]=t4.w; }
    else              { float2 t2=*(const float2*)&h2iS[32*w+i][0]; hv[0]=t2.x; hv[1]=t2.y; }
    #pragma unroll
    for(int e=0;e<N;++e) a3a[e]=fmaf(hv[e], wA3[i], a3a[e]);
  }
  if constexpr(N==4) *(float4*)&P3[w][j][0]=make_float4(a3a[0],a3a[1],a3a[2],a3a[3]);
  else               *(float2*)&P3[w][j][0]=make_float2(a3a[0],a3a[1]);
  __syncthreads();
  if(tid<64){
    float d[N], zn[N];
    #pragma unroll
    for(int e=0;e<N;++e){
      d[e]=P3[0][tid][e]+P3[1][tid][e]+P3[2][tid][e]+P3[3][tid][e]+c_a3;
      zn[e]=zS[tid][e]+adt*d[e];
    }
    if constexpr(N==4) *(float4*)&zS[tid][0]=make_float4(zn[0],zn[1],zn[2],zn[3]);
    else               *(float2*)&zS[tid][0]=make_float2(zn[0],zn[1]);
  }
  __syncthreads();
}

// ---------------- Encoder ----------------
// 1024 blocks x 256 thr. block = (chunk of 2 samples) x (t-pair g: {7-g, g}).
// states: e0=(s0,ta) e1=(s1,ta) e2=(s0,tb) e3=(s1,tb). Phase1 k<sb: 4 states;
// phase2 k<sa: states {0,1}. Weights in VGPRs, K-split over 4 waves.
extern "C" __global__ void __launch_bounds__(256, 2)
k_enc(const float* __restrict__ features,
      const float* __restrict__ feW1, const float* __restrict__ feb1,
      const float* __restrict__ feW2, const float* __restrict__ feb2,
      const float* __restrict__ feW3, const float* __restrict__ feb3,
      const float* __restrict__ A1, const float* __restrict__ a1,
      const float* __restrict__ A2, const float* __restrict__ a2,
      const float* __restrict__ A3, const float* __restrict__ a3,
      const float* __restrict__ pW1, const float* __restrict__ pb1,
      const float* __restrict__ pW2, const float* __restrict__ pb2,
      float* __restrict__ ws_mu, float* __restrict__ ws_lv)
{
  __shared__ float zS[64][4];
  __shared__ float h1S[128][4];
  __shared__ float h2eS[64][4];     // embedding/posterior hidden (64)
  __shared__ float h2iS[128][4];    // IVP hidden2 (128)
  __shared__ float P[4][128][4];
  __shared__ float P3[4][64][4];
  const int tid=threadIdx.x, w=tid>>6, j=tid&63;
  const int g=blockIdx.x&3, chunk=blockIdx.x>>2, s0=chunk*2;
  const int ta=7-g, tb=g, sa=10*ta, sb=10*tb;

  // weight registers (K-split)
  float wA1[16][2], wA2[32][2], wA3[32];
  #pragma unroll
  for(int i=0;i<16;++i){ float2 v=*(const float2*)&A1[(16*w+i)*128+2*j]; wA1[i][0]=v.x; wA1[i][1]=v.y; }
  #pragma unroll
  for(int i=0;i<32;++i){ float2 v=*(const float2*)&A2[(32*w+i)*128+2*j]; wA2[i][0]=v.x; wA2[i][1]=v.y; }
  #pragma unroll
  for(int i=0;i<32;++i){ wA3[i]=A3[(32*w+i)*64+j]; }

  // combine-stage per-thread constants
  float c_a1=0.f, c_wt=0.f, c_a2=0.f, c_a3=0.f;
  if(tid<128){ c_a1=a1[tid]; c_wt=A1[64*128+tid]; c_a2=a2[tid]; }
  if(tid<64){ c_a3=a3[tid]; }

  // ---- embedding: wave w computes state e=w ----
  {
    const int s = s0 + (w&1);
    const int tv = (w<2)?ta:tb;
    const float* f = features + ((size_t)s*TT + tv)*6;
    float x[6];
    #pragma unroll
    for(int i=0;i<6;++i) x[i]=f[i];
    float h0=feb1[2*j], h1v=feb1[2*j+1];
    #pragma unroll
    for(int i=0;i<6;++i){ float2 wv=*(const float2*)&feW1[i*128+2*j]; h0=fmaf(x[i],wv.x,h0); h1v=fmaf(x[i],wv.y,h1v); }
    h1S[2*j][w]=lrelu(h0); h1S[2*j+1][w]=lrelu(h1v);
    __syncthreads();
    float acc=feb2[j];
    #pragma unroll 8
    for(int i=0;i<128;++i) acc=fmaf(h1S[i][w], feW2[i*64+j], acc);
    h2eS[j][w]=lrelu(acc);
    __syncthreads();
    float zz=feb3[j];
    #pragma unroll 8
    for(int i=0;i<64;++i) zz=fmaf(h2eS[i][w], feW3[i*64+j], zz);
    zS[j][w]=zz;
  }
  __syncthreads();

  // ---- IVP: lockstep both trajectories (adt = -0.1, t_k = 0.1k) ----
  for(int k=0;k<sb;++k)
    ivp_step<4>(tid,w,j,0.1f*(float)k,-0.1f,wA1,wA2,wA3,c_a1,c_wt,c_a2,c_a3,zS,h1S,h2iS,P,P3);
  for(int k=sb;k<sa;++k)
    ivp_step<2>(tid,w,j,0.1f*(float)k,-0.1f,wA1,wA2,wA3,c_a1,c_wt,c_a2,c_a3,zS,h1S,h2iS,P,P3);

  // ---- posterior: wave w handles state e=w ----
  {
    float acc=pb1[j];
    #pragma unroll 8
    for(int i=0;i<64;++i) acc=fmaf(zS[i][w], pW1[i*64+j], acc);
    __syncthreads();
    h2eS[j][w]=lrelu(acc);
    __syncthreads();
    float m=pb2[j], l=pb2[j+64];
    #pragma unroll 8
    for(int i=0;i<64;++i){ float hv=h2eS[i][w]; m=fmaf(hv,pW2[i*128+j],m); l=fmaf(hv,pW2[i*128+j+64],l); }
    const int s = s0 + (w&1);
    const int tv = (w<2)?ta:tb;
    size_t o=((size_t)s*TT+tv)*64+j;
    ws_mu[o]=m; ws_lv[o]=l;
  }
}

// ---------------- Decoder ----------------
// 512 blocks x 256 thr, 1 sample each. mix+softmax+reparam, ONE shared 70-step
// trajectory (all _ivp(z0,t) are prefixes), record every 10 steps, rec MLP.
extern "C" __global__ void __launch_bounds__(256, 2)
k_dec(const float* __restrict__ mu_g, const float* __restrict__ lv_g,
      const float* __restrict__ eps,
      const float* __restrict__ mxW1, const float* __restrict__ mxb1,
      const float* __restrict__ mxW2, const float* __restrict__ mxb2,
      const float* __restrict__ A1, const float* __restrict__ a1,
      const float* __restrict__ A2, const float* __restrict__ a2,
      const float* __restrict__ A3, const float* __restrict__ a3,
      const float* __restrict__ rW1, const float* __restrict__ rb1,
      const float* __restrict__ rW2, const float* __restrict__ rb2,
      const float* __restrict__ rW3, const float* __restrict__ rb3,
      float* __restrict__ out)
{
  __shared__ float mu_s[8][64], lv_s[8][64];
  __shared__ float mh[8][32];
  __shared__ float wl[8];
  __shared__ float zS[64];
  __shared__ float h1S[128];
  __shared__ float h2S[128];
  __shared__ float P[4][128];
  __shared__ float P3[4][64];
  __shared__ float LAT[8][64];
  const int tid=threadIdx.x, w=tid>>6, j=tid&63;
  const int b=blockIdx.x;

  for(int idx=tid; idx<512; idx+=256){
    ((float*)mu_s)[idx]=mu_g[(size_t)b*512+idx];
    ((float*)lv_s)[idx]=lv_g[(size_t)b*512+idx];
  }

  // weight registers (K-split)
  float wA1[16][2], wA2[32][2], wA3[32];
  #pragma unroll
  for(int i=0;i<16;++i){ float2 v=*(const float2*)&A1[(16*w+i)*128+2*j]; wA1[i][0]=v.x; wA1[i][1]=v.y; }
  #pragma unroll
  for(int i=0;i<32;++i){ float2 v=*(const float2*)&A2[(32*w+i)*128+2*j]; wA2[i][0]=v.x; wA2[i][1]=v.y; }
  #pragma unroll
  for(int i=0;i<32;++i){ wA3[i]=A3[(32*w+i)*64+j]; }
  float c_a1=0.f, c_wt=0.f, c_a2=0.f, c_a3=0.f;
  if(tid<128){ c_a1=a1[tid]; c_wt=A1[64*128+tid]; c_a2=a2[tid]; }
  if(tid<64){ c_a3=a3[tid]; }
  __syncthreads();

  // mixing hidden: (t,c) per thread
  {
    int t=tid>>5, c=tid&31;
    float a=mxb1[c];
    #pragma unroll 8
    for(int i=0;i<64;++i) a=fmaf(mu_s[t][i], mxW1[i*32+c], a);
    mh[t][c]=lrelu(a);
  }
  __syncthreads();
  if(tid<8){
    float a=mxb2[0];
    #pragma unroll
    for(int i=0;i<32;++i) a=fmaf(mh[tid][i], mxW2[i], a);
    wl[tid]=a;
  }
  __syncthreads();
  if(tid<64){
    float m=-1e30f;
    #pragma unroll
    for(int t=0;t<8;++t) m=fmaxf(m, wl[t]);
    float e[8], S=0.f;
    #pragma unroll
    for(int t=0;t<8;++t){ e[t]=expf(wl[t]-m); S+=e[t]; }
    float inv=1.f/S, mu0=0.f, lv0=0.f;
    #pragma unroll
    for(int t=0;t<8;++t){
      float wt=e[t]*inv;
      mu0=fmaf(wt, mu_s[t][tid], mu0);
      lv0=fmaf(wt, lv_s[t][tid], lv0);
    }
    float z0=fmaf(eps[(size_t)b*64+tid], expf(0.5f*lv0), mu0);
    zS[tid]=z0; LAT[0][tid]=z0;
  }
  __syncthreads();

  // ---- shared 70-step forward trajectory ----
  for(int k=0;k<70;++k){
    float tk=0.1f*(float)k;
    float acc0=0.f, acc1=0.f;
    #pragma unroll
    for(int i=0;i<16;++i){ float zv=zS[16*w+i]; acc0=fmaf(zv,wA1[i][0],acc0); acc1=fmaf(zv,wA1[i][1],acc1); }
    *(float2*)&P[w][2*j]=make_float2(acc0,acc1);
    __syncthreads();
    if(tid<128) h1S[tid]=tanhf(P[0][tid]+P[1][tid]+P[2][tid]+P[3][tid]+tk*c_wt+c_a1);
    __syncthreads();
    acc0=0.f; acc1=0.f;
    #pragma unroll
    for(int i=0;i<32;++i){ float hv=h1S[32*w+i]; acc0=fmaf(hv,wA2[i][0],acc0); acc1=fmaf(hv,wA2[i][1],acc1); }
    *(float2*)&P[w][2*j]=make_float2(acc0,acc1);
    __syncthreads();
    if(tid<128) h2S[tid]=tanhf(P[0][tid]+P[1][tid]+P[2][tid]+P[3][tid]+c_a2);
    __syncthreads();
    float a3a=0.f;
    #pragma unroll
    for(int i=0;i<32;++i) a3a=fmaf(h2S[32*w+i], wA3[i], a3a);
    P3[w][j]=a3a;
    __syncthreads();
    if(tid<64){
      float d=P3[0][tid]+P3[1][tid]+P3[2][tid]+P3[3][tid]+c_a3;
      float z=zS[tid]+0.1f*d;
      zS[tid]=z;
      if(((k+1)%10)==0) LAT[(k+1)/10][tid]=z;
    }
    __syncthreads();
  }

  // ---- reconstruction MLP per t ----
  for(int t=0;t<8;++t){
    {
      int kh=tid>>7, col=tid&127;
      float a=0.f;
      #pragma unroll 8
      for(int i=0;i<32;++i) a=fmaf(LAT[t][32*kh+i], rW1[(32*kh+i)*128+col], a);
      P[kh][col]=a;
    }
    __syncthreads();
    if(tid<128) h1S[tid]=lrelu(P[0][tid]+P[1][tid]+rb1[tid]);
    __syncthreads();
    {
      int kq=tid>>6, col=tid&63;
      float a=0.f;
      #pragma unroll 8
      for(int i=0;i<32;++i) a=fmaf(h1S[32*kq+i], rW2[(32*kq+i)*64+col], a);
      P3[kq][col]=a;
    }
    __syncthreads();
    if(tid<64) h2S[tid]=lrelu(P3[0][tid]+P3[1][tid]+P3[2][tid]+P3[3][tid]+rb2[tid]);
    __syncthreads();
    if(tid<2){
      float a=rb3[tid];
      #pragma unroll 8
      for(int i=0;i<64;++i) a=fmaf(h2S[i], rW3[i*2+tid], a);
      out[((size_t)b*8+t)*2+tid]=a;
    }
    __syncthreads();
  }
}

extern "C" void kernel_launch(void* const* d_in, const int* in_sizes, int n_in,
                              void* d_out, int out_size, void* d_ws, size_t ws_size,
                              hipStream_t stream){
  const float* features=(const float*)d_in[0];
  const float* eps     =(const float*)d_in[1];
  const float* feW1=(const float*)d_in[2];  const float* feb1=(const float*)d_in[3];
  const float* feW2=(const float*)d_in[4];  const float* feb2=(const float*)d_in[5];
  const float* feW3=(const float*)d_in[6];  const float* feb3=(const float*)d_in[7];
  const float* eA1=(const float*)d_in[8];   const float* ea1=(const float*)d_in[9];
  const float* eA2=(const float*)d_in[10];  const float* ea2=(const float*)d_in[11];
  const float* eA3=(const float*)d_in[12];  const float* ea3=(const float*)d_in[13];
  const float* pW1=(const float*)d_in[14];  const float* pb1=(const float*)d_in[15];
  const float* pW2=(const float*)d_in[16];  const float* pb2=(const float*)d_in[17];
  const float* mxW1=(const float*)d_in[18]; const float* mxb1=(const float*)d_in[19];
  const float* mxW2=(const float*)d_in[20]; const float* mxb2=(const float*)d_in[21];
  const float* dA1=(const float*)d_in[22];  const float* da1=(const float*)d_in[23];
  const float* dA2=(const float*)d_in[24];  const float* da2=(const float*)d_in[25];
  const float* dA3=(const float*)d_in[26];  const float* da3=(const float*)d_in[27];
  const float* rW1=(const float*)d_in[28];  const float* rb1=(const float*)d_in[29];
  const float* rW2=(const float*)d_in[30];  const float* rb2=(const float*)d_in[31];
  const float* rW3=(const float*)d_in[32];  const float* rb3=(const float*)d_in[33];

  float* ws_mu=(float*)d_ws;
  float* ws_lv=ws_mu + 512*8*64;

  k_enc<<<dim3(1024),dim3(256),0,stream>>>(features,
      feW1,feb1,feW2,feb2,feW3,feb3,
      eA1,ea1,eA2,ea2,eA3,ea3,
      pW1,pb1,pW2,pb2,
      ws_mu, ws_lv);
  k_dec<<<dim3(512),dim3(256),0,stream>>>(ws_mu, ws_lv, eps,
      mxW1,mxb1,mxW2,mxb2,
      dA1,da1,dA2,da2,dA3,da3,
      rW1,rb1,rW2,rb2,rW3,rb3,
      (float*)d_out);
}